// Round 6
// baseline (634.469 us; speedup 1.0000x reference)
//
#include <hip/hip_runtime.h>
#include <hip/hip_bf16.h>

// Problem constants
#define BATCH 4096
#define G     14271   // genes = GEMM K dim
#define H     24      // gene sets
#define KT    446     // ceil(G/32) k-tiles (446*32 = 14272, 1 pad slot)
#define NIT   223     // K iterations of BK=64 (2 k-tiles each)
#define MB1   223     // ceil(G/64) m-blocks for B-GEMM (full K, no split)
#define MBX   64      // 4096/64 m-blocks for x GEMMs
#define SX    16      // k-splits x GEMMs
#define IPSX  14      // iters per split x GEMMs (last = 13)
#define LDSTR 68      // LDS row stride in dwords (64 + 4 pad -> conflict-free b128)
#define FMAX  3.402823466e38f

typedef __bf16 bf16x8 __attribute__((ext_vector_type(8)));
typedef float  f32x4  __attribute__((ext_vector_type(4)));
typedef unsigned short u16x8 __attribute__((ext_vector_type(8)));
typedef unsigned short u16x4 __attribute__((ext_vector_type(4)));

__device__ inline unsigned short bf16_bits(float f) {
    __bf16 h = (__bf16)f;
    return __builtin_bit_cast(unsigned short, h);
}
__device__ inline float bits_to_f32(unsigned short b) {
    return __builtin_bit_cast(float, (unsigned int)b << 16);
}

// ---------------- fused counts + fragment fill ----------------
// One wave per ktile (two passes): stage w[kt*32..+32)[0..24) into LDS via
// coalesced loads, then emit W01f (NT=2) and C2f (NT=3, w-cols only) frags
// with coalesced 16B stores, and per-column counts via int atomics.
// Frag layout: frag[(ktile*NT+nt)*64 + lane][j] = Wc[ktile*32 + (lane>>4)*8 + j][nt*16 + (lane&15)]
__global__ __launch_bounds__(256) void k_fillcnt(const float* __restrict__ w,
                                                 unsigned short* __restrict__ W01f,
                                                 unsigned short* __restrict__ C2f,
                                                 int* __restrict__ counts) {
    __shared__ float wt[4][32 * 24];
    int wave = threadIdx.x >> 6, lane = threadIdx.x & 63;
    int wid0 = blockIdx.x * 4 + wave;        // 0..223
#pragma unroll
    for (int half = 0; half < 2; ++half) {
        int kt = wid0 + half * 224;
        if (kt >= KT) break;
        // stage: lane covers elements [lane*12, lane*12+12) of the 768-float tile
        {
            int rloc = lane >> 1;
            int grow = kt * 32 + rloc;
            int grc  = (grow < G) ? grow : (G - 1);   // clamp; validity re-checked at use
            int col0 = (lane & 1) * 12;
            const float4* src = reinterpret_cast<const float4*>(w + (long)grc * 24 + col0);
            float* dst = &wt[wave][rloc * 24 + col0];
#pragma unroll
            for (int q = 0; q < 3; ++q) {
                float4 v = src[q];
                dst[q * 4 + 0] = v.x; dst[q * 4 + 1] = v.y;
                dst[q * 4 + 2] = v.z; dst[q * 4 + 3] = v.w;
            }
        }
        int r16 = lane & 15, kloc = (lane >> 4) * 8;
        // W01f: nt = 0,1 (cols >= 24 are zero pad)
#pragma unroll
        for (int nt = 0; nt < 2; ++nt) {
            int col = nt * 16 + r16;
            u16x8 v;
#pragma unroll
            for (int j = 0; j < 8; ++j) {
                int k = kt * 32 + kloc + j;
                bool bit = (k < G) && (col < 24) && (wt[wave][(kloc + j) * 24 + col] > 0.0f);
                v[j] = bit ? (unsigned short)0x3F80 : (unsigned short)0;
            }
            *reinterpret_cast<u16x8*>(W01f + ((long)(kt * 2 + nt) * 64 + lane) * 8) = v;
        }
        // C2f: nt = 0 (cols 0..15), nt = 1 lanes with col < 24; gs region untouched
#pragma unroll
        for (int nt = 0; nt < 2; ++nt) {
            int col = nt * 16 + r16;
            if (col >= 24) continue;
            u16x8 v;
#pragma unroll
            for (int j = 0; j < 8; ++j) {
                int k = kt * 32 + kloc + j;
                bool bit = (k < G) && (wt[wave][(kloc + j) * 24 + col] > 0.0f);
                v[j] = bit ? (unsigned short)0x3F80 : (unsigned short)0;
            }
            *reinterpret_cast<u16x8*>(C2f + ((long)(kt * 3 + nt) * 64 + lane) * 8) = v;
        }
        // counts: lanes 0..23 sum their column over the 32 rows (int atomics: deterministic)
        if (lane < 24) {
            int c = 0;
#pragma unroll
            for (int r = 0; r < 32; ++r)
                c += ((kt * 32 + r) < G && wt[wave][r * 24 + lane] > 0.0f) ? 1 : 0;
            atomicAdd(&counts[lane], c);
        }
    }
}

// consts: [0..23]=n  [24]=maxrank  [32..55]=uc_a  [56..79]=c2  [80..103]=inv_n
//         [104..127]=S (k_sumS)    [128..175]=mu  [176..223]=out_w*rsig (k3b)
__global__ void k_consts(const int* __restrict__ counts,
                         const float* __restrict__ maxrank_p,
                         float* __restrict__ consts) {
    __shared__ float smr;
    int t = threadIdx.x;
    if (t == 0) {
        int nm = 0;
        for (int h = 0; h < H; ++h) nm = max(nm, counts[h]);
        float mp = maxrank_p[0];
        if (mp < 0.0f) mp = 0.0f;
        smr = (float)nm + 10.0f + mp * 1000.0f;
        consts[24] = smr;
    }
    __syncthreads();
    if (t < H) {
        float n  = (float)counts[t];
        float mr = smr;
        float c1 = n * (n + 1.0f) * 0.5f;
        float c2 = 1.0f / (n * mr);
        consts[t]      = n;
        consts[32 + t] = 1.0f + c1 * c2;
        consts[56 + t] = c2;
        consts[80 + t] = 1.0f / n;
    }
}

// ---------------- GEMM core (R2 structure: LDS-DMA + dbuf + syncthreads) -----

__device__ inline void stage_tile(const float* __restrict__ A, int M, int row0,
                                  int k0, bool clampk, float* buf,
                                  int wave, int lane) {
    int k = k0 + lane;
    if (clampk) k = (k < G) ? k : (G - 1);
#pragma unroll
    for (int i = 0; i < 16; ++i) {
        int r = wave * 16 + i;
        int grow = row0 + r;
        grow = (grow < M) ? grow : (M - 1);
        const float* src = A + (long)grow * G + k;
        __builtin_amdgcn_global_load_lds(
            (const __attribute__((address_space(1))) void*)src,
            (__attribute__((address_space(3))) void*)(buf + r * LDSTR),
            4, 0, 0);
    }
}

template <int NT>
__device__ inline void consume_tiles(const float* __restrict__ buf,
                                     const unsigned short* __restrict__ Wf,
                                     int ktile0, float mr, f32x4* acc,
                                     int wave, int lane) {
    int r = lane & 15, sub = lane >> 4;
    const float* rowp = buf + (wave * 16 + r) * LDSTR + sub * 8;
#pragma unroll
    for (int kt = 0; kt < 2; ++kt) {
        const float4* p = reinterpret_cast<const float4*>(rowp + kt * 32);
        float4 lo = p[0];
        float4 hi = p[1];
        float a[8] = {lo.x, lo.y, lo.z, lo.w, hi.x, hi.y, hi.z, hi.w};
        bf16x8 af;
#pragma unroll
        for (int j = 0; j < 8; ++j) af[j] = (__bf16)fminf(a[j], mr);
        const unsigned short* fb = Wf + ((long)((ktile0 + kt) * NT) * 64 + lane) * 8;
#pragma unroll
        for (int nt = 0; nt < NT; ++nt) {
            bf16x8 bfr = *reinterpret_cast<const bf16x8*>(fb + (long)nt * 512);
            acc[nt] = __builtin_amdgcn_mfma_f32_16x16x32_bf16(af, bfr, acc[nt], 0, 0, 0);
        }
    }
}

// 64-row x (NT*16)-col accumulate over iters [it0,it1); no output write here.
template <int NT>
__device__ inline void gemm_core(const float* __restrict__ A, int M, int row0,
                                 const unsigned short* __restrict__ Wf, float mr,
                                 int it0, int it1, f32x4* acc,
                                 int wave, int lane) {
    __shared__ __align__(16) float sbuf[2][64 * LDSTR];
#pragma unroll
    for (int nt = 0; nt < NT; ++nt) acc[nt] = (f32x4){0.f, 0.f, 0.f, 0.f};
    stage_tile(A, M, row0, it0 * 64, it0 == NIT - 1, sbuf[0], wave, lane);
    __syncthreads();
    int cur = 0;
    for (int it = it0; it < it1; ++it) {
        if (it + 1 < it1)
            stage_tile(A, M, row0, (it + 1) * 64, (it + 1) == NIT - 1,
                       sbuf[cur ^ 1], wave, lane);
        consume_tiles<NT>(sbuf[cur], Wf, it * 2, mr, acc, wave, lane);
        __syncthreads();
        cur ^= 1;
    }
}

// merged: B-GEMM (223 blocks, full K, gs epilogue) + rank GEMM (1024 blocks, split 16)
__global__ __launch_bounds__(256) void k_gemm2(
    const float* __restrict__ Bmat, const float* __restrict__ xrank,
    const unsigned short* __restrict__ W01f, const float* __restrict__ consts,
    unsigned short* __restrict__ C2f, float* __restrict__ blockS,
    float* __restrict__ rp) {
    int bid = blockIdx.x;
    int wave = threadIdx.x >> 6, lane = threadIdx.x & 63;
    int r16 = lane & 15, sub = lane >> 4;
    f32x4 acc[2];
    if (bid < MB1) {
        // ---- B @ W01 -> gs, written bf16 into C2f frag cols 24..47 ----
        int mblk = bid, row0 = mblk * 64;
        gemm_core<2>(Bmat, G, row0, W01f, FMAX, 0, NIT, acc, wave, lane);
        int gbase = row0 + wave * 16 + sub * 4;   // 4 consecutive genes per lane
        int ktile = gbase >> 5;
        int j0    = gbase & 7;                     // 0 or 4
        int lsub  = (gbase >> 3) & 3;
        float colsum[2];
#pragma unroll
        for (int nt = 0; nt < 2; ++nt) {
            u16x4 bits;
            float cs = 0.0f;
#pragma unroll
            for (int rr = 0; rr < 4; ++rr) {
                int g = gbase + rr;
                unsigned short b = (g < G) ? bf16_bits(acc[nt][rr]) : (unsigned short)0;
                bits[rr] = b;
                cs += bits_to_f32(b);    // S from rounded values (self-consistent)
            }
            colsum[nt] = cs;
            int col = nt * 16 + r16;     // gs column h
            if (col < 24) {
                int c = 24 + col;        // C2f column
                int ntp = c >> 4, lanep = lsub * 16 + (c & 15);
                *reinterpret_cast<u16x4*>(
                    C2f + ((long)(ktile * 3 + ntp) * 64 + lanep) * 8 + j0) = bits;
            }
        }
        // deterministic block colsum -> blockS[mblk][24]
        float v0 = colsum[0], v1 = colsum[1];
        v0 += __shfl_xor(v0, 16); v0 += __shfl_xor(v0, 32);
        v1 += __shfl_xor(v1, 16); v1 += __shfl_xor(v1, 32);
        __shared__ float sred[4][32];
        if (sub == 0) { sred[wave][r16] = v0; sred[wave][16 + r16] = v1; }
        __syncthreads();
        if (threadIdx.x < 24) {
            int t = threadIdx.x;
            blockS[mblk * 24 + t] =
                sred[0][t] + sred[1][t] + sred[2][t] + sred[3][t];
        }
    } else {
        // ---- clamp(x_rank) @ W01, k-split partials ----
        int t = bid - MB1;
        int mblk = t >> 4, split = t & 15;
        int it0 = split * IPSX;
        int it1 = min(it0 + IPSX, NIT);
        int row0 = mblk * 64;
        gemm_core<2>(xrank, BATCH, row0, W01f, consts[24], it0, it1, acc, wave, lane);
        float* outp = rp + (long)split * BATCH * 32;
        int orow0 = row0 + wave * 16 + sub * 4;
#pragma unroll
        for (int nt = 0; nt < 2; ++nt)
#pragma unroll
            for (int rr = 0; rr < 4; ++rr)
                outp[(long)(orow0 + rr) * 32 + nt * 16 + r16] = acc[nt][rr];
    }
}

__global__ __launch_bounds__(256) void k_gemm3(
    const float* __restrict__ xlog2, const unsigned short* __restrict__ C2f,
    float* __restrict__ lp) {
    int bid = blockIdx.x;
    int wave = threadIdx.x >> 6, lane = threadIdx.x & 63;
    int r16 = lane & 15, sub = lane >> 4;
    int mblk = bid >> 4, split = bid & 15;
    int it0 = split * IPSX;
    int it1 = min(it0 + IPSX, NIT);
    int row0 = mblk * 64;
    f32x4 acc[3];
    gemm_core<3>(xlog2, BATCH, row0, C2f, FMAX, it0, it1, acc, wave, lane);
    float* outp = lp + (long)split * BATCH * 48;
    int orow0 = row0 + wave * 16 + sub * 4;
#pragma unroll
    for (int nt = 0; nt < 3; ++nt)
#pragma unroll
        for (int rr = 0; rr < 4; ++rr)
            outp[(long)(orow0 + rr) * 48 + nt * 16 + r16] = acc[nt][rr];
}

__global__ void k_sumS(const float* __restrict__ blockS, float* __restrict__ consts) {
    int t = threadIdx.x;
    if (t < H) {
        float s = 0.0f;
        for (int b = 0; b < MB1; ++b) s += blockS[b * 24 + t];
        consts[104 + t] = s;
    }
}

// reduce x-GEMM partials, apply UCell/AMS transforms -> R_all [4096 x 48]
__global__ __launch_bounds__(256) void k3a(const float* __restrict__ rp,
                                           const float* __restrict__ lp,
                                           const float* __restrict__ consts,
                                           float* __restrict__ R_all) {
    int e = blockIdx.x * 256 + threadIdx.x;
    if (e >= BATCH * 48) return;
    int b = e / 48, c = e % 48;
    float v;
    if (c < 24) {
        float s = 0.0f;
        for (int sp = 0; sp < SX; ++sp) s += rp[((long)sp * BATCH + b) * 32 + c];
        v = consts[32 + c] - s * consts[56 + c];
    } else {
        int h = c - 24;
        float raw = 0.0f, bg = 0.0f;
        for (int sp = 0; sp < SX; ++sp) {
            const float* base = lp + ((long)sp * BATCH + b) * 48;
            raw += base[h];
            bg  += base[24 + h];
        }
        v = raw * consts[80 + h] - bg / consts[104 + h];
    }
    R_all[e] = v;
}

// per-column batch stats (f64), fold out_w into coef
__global__ __launch_bounds__(256) void k3b(const float* __restrict__ R_all,
                                           const float* __restrict__ out_w,
                                           float* __restrict__ consts) {
    int c = blockIdx.x;
    double s = 0.0, s2 = 0.0;
    for (int b = threadIdx.x; b < BATCH; b += 256) {
        double x = (double)R_all[(long)b * 48 + c];
        s += x; s2 += x * x;
    }
    __shared__ double sh1[256], sh2[256];
    sh1[threadIdx.x] = s; sh2[threadIdx.x] = s2;
    __syncthreads();
    for (int off = 128; off > 0; off >>= 1) {
        if (threadIdx.x < off) {
            sh1[threadIdx.x] += sh1[threadIdx.x + off];
            sh2[threadIdx.x] += sh2[threadIdx.x + off];
        }
        __syncthreads();
    }
    if (threadIdx.x == 0) {
        double mu  = sh1[0] / (double)BATCH;
        double var = sh2[0] / (double)BATCH - mu * mu;
        float rs = (float)(1.0 / sqrt(var + 1e-5));
        consts[128 + c] = (float)mu;
        consts[176 + c] = out_w[c] * rs;
    }
}

__global__ void k3c(const float* __restrict__ R_all, const float* __restrict__ consts,
                    const float* __restrict__ out_b, float* __restrict__ out) {
    int b = blockIdx.x * blockDim.x + threadIdx.x;
    if (b < BATCH) {
        float acc = out_b[0];
#pragma unroll
        for (int c = 0; c < 48; ++c)
            acc += consts[176 + c] * (R_all[(long)b * 48 + c] - consts[128 + c]);
        out[b] = acc;
    }
}

// ---------------- launch ----------------

extern "C" void kernel_launch(void* const* d_in, const int* in_sizes, int n_in,
                              void* d_out, int out_size, void* d_ws, size_t ws_size,
                              hipStream_t stream) {
    const float* x_rank    = (const float*)d_in[0];
    const float* x_log2    = (const float*)d_in[1];
    const float* Bmat      = (const float*)d_in[2];
    const float* weight    = (const float*)d_in[3];
    const float* maxrank_p = (const float*)d_in[4];
    const float* out_w     = (const float*)d_in[5];
    const float* out_b     = (const float*)d_in[6];

    char* ws = (char*)d_ws;
    size_t off = 0;
    auto alloc = [&](size_t bytes) {
        void* p = (void*)(ws + off);
        off = (off + bytes + 255) & ~(size_t)255;
        return p;
    };
    float*          consts = (float*)alloc(256 * 4);
    int*            counts = (int*)alloc(128);
    float*          blockS = (float*)alloc((size_t)MB1 * 24 * 4);
    unsigned short* W01f   = (unsigned short*)alloc((size_t)KT * 2 * 64 * 8 * 2);
    unsigned short* C2f    = (unsigned short*)alloc((size_t)KT * 3 * 64 * 8 * 2);
    float*          rp     = (float*)alloc((size_t)SX * BATCH * 32 * 4);
    float*          lp     = (float*)alloc((size_t)SX * BATCH * 48 * 4);
    float*          R_all  = (float*)alloc((size_t)BATCH * 48 * 4);
    (void)ws_size; (void)in_sizes; (void)n_in; (void)out_size;

    hipMemsetAsync(counts, 0, 128, stream);
    k_fillcnt <<<56, 256, 0, stream>>>(weight, W01f, C2f, counts);
    k_consts  <<<1, 64, 0, stream>>>(counts, maxrank_p, consts);
    k_gemm2   <<<MB1 + MBX * SX, 256, 0, stream>>>(Bmat, x_rank, W01f, consts,
                                                   C2f, blockS, rp);
    k_gemm3   <<<MBX * SX, 256, 0, stream>>>(x_log2, C2f, lp);
    k_sumS    <<<1, 64, 0, stream>>>(blockS, consts);
    k3a       <<<BATCH * 48 / 256, 256, 0, stream>>>(rp, lp, consts, R_all);
    k3b       <<<48, 256, 0, stream>>>(R_all, out_w, consts);
    k3c       <<<16, 256, 0, stream>>>(R_all, consts, out_b, (float*)d_out);
}

// Round 7
// 350.870 us; speedup vs baseline: 1.8083x; 1.8083x over previous
//
#include <hip/hip_runtime.h>
#include <hip/hip_bf16.h>

// Problem constants
#define BATCH 4096
#define G     14271   // genes = GEMM K dim
#define H     24      // gene sets
#define KT    446     // ceil(G/32) k-tiles (446*32 = 14272, 1 pad slot)
#define NIT   223     // K iterations of BK=64 (2 k-tiles each)
#define MB1   223     // ceil(G/64) m-blocks for B-GEMM
#define MBX   64      // 4096/64 m-blocks for x GEMMs
#define S1    8       // k-splits B-GEMM
#define SX    16      // k-splits x GEMMs
#define IPS1  28      // iters per split B-GEMM (last = 27)
#define IPSX  14      // iters per split x GEMMs (last = 13)
#define GP    14272   // padded G rows for partial buffer
#define LDR   72      // LDS row stride in bf16 elements (64 + 8 pad -> 2-way-free b128)
#define FMAX  3.402823466e38f

typedef __bf16 bf16x8 __attribute__((ext_vector_type(8)));
typedef float  f32x4  __attribute__((ext_vector_type(4)));
typedef float  f32x4u __attribute__((ext_vector_type(4), aligned(4)));  // align-4 dwordx4
typedef unsigned short u16x8 __attribute__((ext_vector_type(8)));
typedef unsigned short u16x4 __attribute__((ext_vector_type(4)));

__device__ inline unsigned short bf16_bits(float f) {
    __bf16 h = (__bf16)f;
    return __builtin_bit_cast(unsigned short, h);
}
__device__ inline float bits_to_f32(unsigned short b) {
    return __builtin_bit_cast(float, (unsigned int)b << 16);
}

// ---------------- fused counts + fragment fill (R6 version, proven) ----------
// One wave per ktile (two passes): stage w[kt*32..+32)[0..24) into LDS via
// coalesced loads, emit W01f (NT=2) and C2f (NT=3, w-cols only) frags with
// coalesced 16B stores, and per-column counts via int atomics (deterministic).
// Frag layout: frag[(ktile*NT+nt)*64 + lane][j] = Wc[ktile*32+(lane>>4)*8+j][nt*16+(lane&15)]
__global__ __launch_bounds__(256) void k_fillcnt(const float* __restrict__ w,
                                                 unsigned short* __restrict__ W01f,
                                                 unsigned short* __restrict__ C2f,
                                                 int* __restrict__ counts) {
    __shared__ float wt[4][32 * 24];
    int wave = threadIdx.x >> 6, lane = threadIdx.x & 63;
    int wid0 = blockIdx.x * 4 + wave;        // 0..223
#pragma unroll
    for (int half = 0; half < 2; ++half) {
        int kt = wid0 + half * 224;
        if (kt >= KT) break;
        {
            int rloc = lane >> 1;
            int grow = kt * 32 + rloc;
            int grc  = (grow < G) ? grow : (G - 1);
            int col0 = (lane & 1) * 12;
            const float4* src = reinterpret_cast<const float4*>(w + (long)grc * 24 + col0);
            float* dst = &wt[wave][rloc * 24 + col0];
#pragma unroll
            for (int q = 0; q < 3; ++q) {
                float4 v = src[q];
                dst[q * 4 + 0] = v.x; dst[q * 4 + 1] = v.y;
                dst[q * 4 + 2] = v.z; dst[q * 4 + 3] = v.w;
            }
        }
        int r16 = lane & 15, kloc = (lane >> 4) * 8;
#pragma unroll
        for (int nt = 0; nt < 2; ++nt) {
            int col = nt * 16 + r16;
            u16x8 v;
#pragma unroll
            for (int j = 0; j < 8; ++j) {
                int k = kt * 32 + kloc + j;
                bool bit = (k < G) && (col < 24) && (wt[wave][(kloc + j) * 24 + col] > 0.0f);
                v[j] = bit ? (unsigned short)0x3F80 : (unsigned short)0;
            }
            *reinterpret_cast<u16x8*>(W01f + ((long)(kt * 2 + nt) * 64 + lane) * 8) = v;
        }
#pragma unroll
        for (int nt = 0; nt < 2; ++nt) {
            int col = nt * 16 + r16;
            if (col >= 24) continue;
            u16x8 v;
#pragma unroll
            for (int j = 0; j < 8; ++j) {
                int k = kt * 32 + kloc + j;
                bool bit = (k < G) && (wt[wave][(kloc + j) * 24 + col] > 0.0f);
                v[j] = bit ? (unsigned short)0x3F80 : (unsigned short)0;
            }
            *reinterpret_cast<u16x8*>(C2f + ((long)(kt * 3 + nt) * 64 + lane) * 8) = v;
        }
        if (lane < 24) {
            int c = 0;
#pragma unroll
            for (int r = 0; r < 32; ++r)
                c += ((kt * 32 + r) < G && wt[wave][r * 24 + lane] > 0.0f) ? 1 : 0;
            atomicAdd(&counts[lane], c);
        }
    }
}

// consts: [0..23]=n  [24]=maxrank  [32..55]=uc_a  [56..79]=c2  [80..103]=inv_n
//         [104..127]=S (k_sumS)    [128..175]=mu  [176..223]=out_w*rsig (k3b)
__global__ void k_consts(const int* __restrict__ counts,
                         const float* __restrict__ maxrank_p,
                         float* __restrict__ consts) {
    __shared__ float smr;
    int t = threadIdx.x;
    if (t == 0) {
        int nm = 0;
        for (int h = 0; h < H; ++h) nm = max(nm, counts[h]);
        float mp = maxrank_p[0];
        if (mp < 0.0f) mp = 0.0f;
        smr = (float)nm + 10.0f + mp * 1000.0f;
        consts[24] = smr;
    }
    __syncthreads();
    if (t < H) {
        float n  = (float)counts[t];
        float mr = smr;
        float c1 = n * (n + 1.0f) * 0.5f;
        float c2 = 1.0f / (n * mr);
        consts[t]      = n;
        consts[32 + t] = 1.0f + c1 * c2;
        consts[56 + t] = c2;
        consts[80 + t] = 1.0f / n;
    }
}

// ---------------- GEMM core: reg-staged, bf16 LDS, barrierless, 8 blocks/CU --
// LDS tile: [64 rows][72 bf16] (pad 8 -> ds_read_b128 2-way = free).
// Each wave stages AND consumes only its own 16 rows -> no barriers at all.
// clamp + bf16 round happen in registers at stage time (numerics identical to
// doing them at consume time: same value, same rounding point).

__device__ inline void stage_load(const float* __restrict__ A, int M, int row0,
                                  int k0, bool tail, int wave, int lane,
                                  f32x4u* v) {
    int c4 = (lane & 15) * 4;
#pragma unroll
    for (int m = 0; m < 4; ++m) {
        int grow = row0 + wave * 16 + m * 4 + (lane >> 4);
        grow = (grow < M) ? grow : (M - 1);
        const float* rp = A + (long)grow * G;
        if (!tail) {
            v[m] = *reinterpret_cast<const f32x4u*>(rp + k0 + c4);
        } else {
            f32x4u t;
#pragma unroll
            for (int i = 0; i < 4; ++i) {
                int k = k0 + c4 + i;
                t[i] = rp[(k < G) ? k : (G - 1)];   // k>=G slots hit zero frags
            }
            v[m] = t;
        }
    }
}

__device__ inline void stage_write(unsigned short* buf, float mr,
                                   int wave, int lane, const f32x4u* v) {
#pragma unroll
    for (int m = 0; m < 4; ++m) {
        int row = wave * 16 + m * 4 + (lane >> 4);
        u16x4 b;
#pragma unroll
        for (int i = 0; i < 4; ++i) b[i] = bf16_bits(fminf(v[m][i], mr));
        *reinterpret_cast<u16x4*>(buf + row * LDR + (lane & 15) * 4) = b;
    }
}

template <int NT>
__device__ inline void consume_tiles(const unsigned short* __restrict__ buf,
                                     const unsigned short* __restrict__ Wf,
                                     int ktile0, f32x4* acc, int wave, int lane) {
    int r = lane & 15, sub = lane >> 4;
    const unsigned short* rowp = buf + (wave * 16 + r) * LDR;
#pragma unroll
    for (int kt = 0; kt < 2; ++kt) {
        bf16x8 af = *reinterpret_cast<const bf16x8*>(rowp + kt * 32 + sub * 8);
        const unsigned short* fb = Wf + ((long)((ktile0 + kt) * NT) * 64 + lane) * 8;
#pragma unroll
        for (int nt = 0; nt < NT; ++nt) {
            bf16x8 bfr = *reinterpret_cast<const bf16x8*>(fb + (long)nt * 512);
            acc[nt] = __builtin_amdgcn_mfma_f32_16x16x32_bf16(af, bfr, acc[nt], 0, 0, 0);
        }
    }
}

// 64-row x (NT*16)-col accumulate over iters [it0,it1). 4 waves/block, each an
// independent pipeline; dbuf; global->reg loads for tile n+1 issue before
// consume(n), reg->LDS writes after (T14; compiler inserts exact waits).
template <int NT>
__device__ inline void gemm_core(const float* __restrict__ A, int M, int row0,
                                 const unsigned short* __restrict__ Wf, float mr,
                                 int it0, int it1, f32x4* acc,
                                 int wave, int lane) {
    __shared__ __align__(16) unsigned short sb[2][64 * LDR];
#pragma unroll
    for (int nt = 0; nt < NT; ++nt) acc[nt] = (f32x4){0.f, 0.f, 0.f, 0.f};
    f32x4u v[4];
    stage_load(A, M, row0, it0 * 64, it0 == NIT - 1, wave, lane, v);
    stage_write(sb[0], mr, wave, lane, v);
    int cur = 0;
    for (int it = it0; it < it1 - 1; ++it) {
        int nxt = it + 1;
        stage_load(A, M, row0, nxt * 64, nxt == NIT - 1, wave, lane, v);
        consume_tiles<NT>(sb[cur], Wf, it * 2, acc, wave, lane);
        stage_write(sb[cur ^ 1], mr, wave, lane, v);
        cur ^= 1;
    }
    consume_tiles<NT>(sb[cur], Wf, (it1 - 1) * 2, acc, wave, lane);
}

// merged: B-GEMM (split 8 -> p1 partials) + rank GEMM (split 16 -> rp partials)
__global__ __launch_bounds__(256) void k_gemm2(
    const float* __restrict__ Bmat, const float* __restrict__ xrank,
    const unsigned short* __restrict__ W01f, const float* __restrict__ consts,
    float* __restrict__ p1, float* __restrict__ rp) {
    int bid = blockIdx.x;
    int wave = threadIdx.x >> 6, lane = threadIdx.x & 63;
    int r16 = lane & 15, sub = lane >> 4;
    f32x4 acc[2];
    const float* A;
    int M, mblk, it0, it1;
    float mr;
    float* outp;
    if (bid < MB1 * S1) {
        mblk = bid >> 3; int split = bid & 7;
        it0 = split * IPS1; it1 = min(it0 + IPS1, NIT);
        A = Bmat; M = G; mr = FMAX;
        outp = p1 + (long)split * GP * 32;
    } else {
        int t = bid - MB1 * S1;
        mblk = t >> 4; int split = t & 15;
        it0 = split * IPSX; it1 = min(it0 + IPSX, NIT);
        A = xrank; M = BATCH; mr = consts[24];
        outp = rp + (long)split * BATCH * 32;
    }
    int row0 = mblk * 64;
    gemm_core<2>(A, M, row0, W01f, mr, it0, it1, acc, wave, lane);
    int orow0 = row0 + wave * 16 + sub * 4;
#pragma unroll
    for (int nt = 0; nt < 2; ++nt)
#pragma unroll
        for (int rr = 0; rr < 4; ++rr) {
            int orow = orow0 + rr;
            if (orow < M) outp[(long)orow * 32 + nt * 16 + r16] = acc[nt][rr];
        }
}

__global__ __launch_bounds__(256) void k_gemm3(
    const float* __restrict__ xlog2, const unsigned short* __restrict__ C2f,
    float* __restrict__ lp) {
    int bid = blockIdx.x;
    int wave = threadIdx.x >> 6, lane = threadIdx.x & 63;
    int r16 = lane & 15, sub = lane >> 4;
    int mblk = bid >> 4, split = bid & 15;
    int it0 = split * IPSX;
    int it1 = min(it0 + IPSX, NIT);
    int row0 = mblk * 64;
    f32x4 acc[3];
    gemm_core<3>(xlog2, BATCH, row0, C2f, FMAX, it0, it1, acc, wave, lane);
    float* outp = lp + (long)split * BATCH * 48;
    int orow0 = row0 + wave * 16 + sub * 4;
#pragma unroll
    for (int nt = 0; nt < 3; ++nt)
#pragma unroll
        for (int rr = 0; rr < 4; ++rr)
            outp[(long)(orow0 + rr) * 48 + nt * 16 + r16] = acc[nt][rr];
}

// reduce B-GEMM k-split partials -> gs (bf16 into C2f frag cols 24..47) + block S partials
__global__ __launch_bounds__(256) void k_reduce1(const float* __restrict__ p1,
                                                 unsigned short* __restrict__ C2f,
                                                 float* __restrict__ blockS) {
    int k = blockIdx.x * 256 + threadIdx.x;  // enumerates frag k-slots
    float gsr[H];
#pragma unroll
    for (int h = 0; h < H; ++h) gsr[h] = 0.0f;
    if (k < GP) {
        if (k < G) {
            for (int sp = 0; sp < S1; ++sp) {
                const float4* r4 = reinterpret_cast<const float4*>(
                    p1 + ((long)sp * GP + k) * 32);
#pragma unroll
                for (int q = 0; q < 6; ++q) {
                    float4 v = r4[q];
                    gsr[q * 4 + 0] += v.x;
                    gsr[q * 4 + 1] += v.y;
                    gsr[q * 4 + 2] += v.z;
                    gsr[q * 4 + 3] += v.w;
                }
            }
        }
        int ktile = k >> 5, j = k & 7, lsub = (k >> 3) & 3;
#pragma unroll
        for (int h = 0; h < H; ++h) {
            unsigned short bits = bf16_bits(gsr[h]);
            int col = 24 + h, nt = col >> 4, lane = lsub * 16 + (col & 15);
            C2f[((long)(ktile * 3 + nt) * 64 + lane) * 8 + j] = bits;
            gsr[h] = bits_to_f32(bits);  // S from the rounded values (self-consistent)
        }
    }
    // deterministic reduction: wave shfl tree, then cross-wave via LDS
    __shared__ float sred[4][H];
    int lane = threadIdx.x & 63, w = threadIdx.x >> 6;
#pragma unroll
    for (int h = 0; h < H; ++h) {
        float v = gsr[h];
        for (int off = 1; off < 64; off <<= 1) v += __shfl_xor(v, off);
        if (lane == 0) sred[w][h] = v;
    }
    __syncthreads();
    if (threadIdx.x < H) {
        float s = sred[0][threadIdx.x] + sred[1][threadIdx.x] +
                  sred[2][threadIdx.x] + sred[3][threadIdx.x];
        blockS[blockIdx.x * H + threadIdx.x] = s;
    }
}

__global__ void k_sumS(const float* __restrict__ blockS, float* __restrict__ consts) {
    int t = threadIdx.x;
    if (t < H) {
        float s = 0.0f;
        for (int b = 0; b < 56; ++b) s += blockS[b * H + t];
        consts[104 + t] = s;
    }
}

// reduce x-GEMM partials, apply UCell/AMS transforms -> R_all [4096 x 48]
__global__ __launch_bounds__(256) void k3a(const float* __restrict__ rp,
                                           const float* __restrict__ lp,
                                           const float* __restrict__ consts,
                                           float* __restrict__ R_all) {
    int e = blockIdx.x * 256 + threadIdx.x;
    if (e >= BATCH * 48) return;
    int b = e / 48, c = e % 48;
    float v;
    if (c < 24) {
        float s = 0.0f;
        for (int sp = 0; sp < SX; ++sp) s += rp[((long)sp * BATCH + b) * 32 + c];
        v = consts[32 + c] - s * consts[56 + c];
    } else {
        int h = c - 24;
        float raw = 0.0f, bg = 0.0f;
        for (int sp = 0; sp < SX; ++sp) {
            const float* base = lp + ((long)sp * BATCH + b) * 48;
            raw += base[h];
            bg  += base[24 + h];
        }
        v = raw * consts[80 + h] - bg / consts[104 + h];
    }
    R_all[e] = v;
}

// per-column batch stats (f64), fold out_w into coef
__global__ __launch_bounds__(256) void k3b(const float* __restrict__ R_all,
                                           const float* __restrict__ out_w,
                                           float* __restrict__ consts) {
    int c = blockIdx.x;
    double s = 0.0, s2 = 0.0;
    for (int b = threadIdx.x; b < BATCH; b += 256) {
        double x = (double)R_all[(long)b * 48 + c];
        s += x; s2 += x * x;
    }
    __shared__ double sh1[256], sh2[256];
    sh1[threadIdx.x] = s; sh2[threadIdx.x] = s2;
    __syncthreads();
    for (int off = 128; off > 0; off >>= 1) {
        if (threadIdx.x < off) {
            sh1[threadIdx.x] += sh1[threadIdx.x + off];
            sh2[threadIdx.x] += sh2[threadIdx.x + off];
        }
        __syncthreads();
    }
    if (threadIdx.x == 0) {
        double mu  = sh1[0] / (double)BATCH;
        double var = sh2[0] / (double)BATCH - mu * mu;
        float rs = (float)(1.0 / sqrt(var + 1e-5));
        consts[128 + c] = (float)mu;
        consts[176 + c] = out_w[c] * rs;
    }
}

__global__ void k3c(const float* __restrict__ R_all, const float* __restrict__ consts,
                    const float* __restrict__ out_b, float* __restrict__ out) {
    int b = blockIdx.x * blockDim.x + threadIdx.x;
    if (b < BATCH) {
        float acc = out_b[0];
#pragma unroll
        for (int c = 0; c < 48; ++c)
            acc += consts[176 + c] * (R_all[(long)b * 48 + c] - consts[128 + c]);
        out[b] = acc;
    }
}

// ---------------- launch ----------------

extern "C" void kernel_launch(void* const* d_in, const int* in_sizes, int n_in,
                              void* d_out, int out_size, void* d_ws, size_t ws_size,
                              hipStream_t stream) {
    const float* x_rank    = (const float*)d_in[0];
    const float* x_log2    = (const float*)d_in[1];
    const float* Bmat      = (const float*)d_in[2];
    const float* weight    = (const float*)d_in[3];
    const float* maxrank_p = (const float*)d_in[4];
    const float* out_w     = (const float*)d_in[5];
    const float* out_b     = (const float*)d_in[6];

    char* ws = (char*)d_ws;
    size_t off = 0;
    auto alloc = [&](size_t bytes) {
        void* p = (void*)(ws + off);
        off = (off + bytes + 255) & ~(size_t)255;
        return p;
    };
    float*          consts = (float*)alloc(256 * 4);
    int*            counts = (int*)alloc(128);
    float*          blockS = (float*)alloc(56 * H * 4);
    unsigned short* W01f   = (unsigned short*)alloc((size_t)KT * 2 * 64 * 8 * 2);
    unsigned short* C2f    = (unsigned short*)alloc((size_t)KT * 3 * 64 * 8 * 2);
    float*          p1     = (float*)alloc((size_t)S1 * GP * 32 * 4);
    float*          rp     = (float*)alloc((size_t)SX * BATCH * 32 * 4);
    float*          lp     = (float*)alloc((size_t)SX * BATCH * 48 * 4);
    float*          R_all  = (float*)alloc((size_t)BATCH * 48 * 4);
    (void)ws_size; (void)in_sizes; (void)n_in; (void)out_size;

    hipMemsetAsync(counts, 0, 128, stream);
    k_fillcnt <<<56, 256, 0, stream>>>(weight, W01f, C2f, counts);
    k_consts  <<<1, 64, 0, stream>>>(counts, maxrank_p, consts);
    k_gemm2   <<<MB1 * S1 + MBX * SX, 256, 0, stream>>>(Bmat, x_rank, W01f, consts, p1, rp);
    k_reduce1 <<<56, 256, 0, stream>>>(p1, C2f, blockS);
    k_sumS    <<<1, 64, 0, stream>>>(blockS, consts);
    k_gemm3   <<<MBX * SX, 256, 0, stream>>>(x_log2, C2f, lp);
    k3a       <<<BATCH * 48 / 256, 256, 0, stream>>>(rp, lp, consts, R_all);
    k3b       <<<48, 256, 0, stream>>>(R_all, out_w, consts);
    k3c       <<<16, 256, 0, stream>>>(R_all, consts, out_b, (float*)d_out);
}

// Round 8
// 340.606 us; speedup vs baseline: 1.8628x; 1.0301x over previous
//
#include <hip/hip_runtime.h>
#include <hip/hip_bf16.h>

// Problem constants
#define BATCH 4096
#define G     14271   // genes = GEMM K dim
#define H     24      // gene sets
#define KT    446     // ceil(G/32) k-tiles (446*32 = 14272, 1 pad slot)
#define NIT   223     // K iterations of BK=64 (2 k-tiles each)
#define MB1   223     // ceil(G/64) m-blocks for B-GEMM
#define MBX   64      // 4096/64 m-blocks for x GEMMs
#define S1    8       // k-splits B-GEMM
#define SX    16      // k-splits x GEMMs
#define IPS1  28      // iters per split B-GEMM (last = 27)
#define IPSX  14      // iters per split x GEMMs (last = 13)
#define GP    14272   // padded G rows for partial buffer
#define LDR   72      // LDS row stride in bf16 elements (64 + 8 pad -> 2-way-free b128)
#define NFC   112     // fillcnt blocks (1 ktile per wave)
#define NRD   56      // reduce1 blocks
#define FMAX  3.402823466e38f

typedef __bf16 bf16x8 __attribute__((ext_vector_type(8)));
typedef float  f32x4  __attribute__((ext_vector_type(4)));
typedef float  f32x4u __attribute__((ext_vector_type(4), aligned(4)));  // align-4 dwordx4
typedef unsigned short u16x8 __attribute__((ext_vector_type(8)));
typedef unsigned short u16x4 __attribute__((ext_vector_type(4)));

__device__ inline unsigned short bf16_bits(float f) {
    __bf16 h = (__bf16)f;
    return __builtin_bit_cast(unsigned short, h);
}
__device__ inline float bits_to_f32(unsigned short b) {
    return __builtin_bit_cast(float, (unsigned int)b << 16);
}

// ---------------- fused fragment fill + per-block counts (no atomics) --------
// One wave per ktile: stage w[kt*32..+32)[0..24) into LDS (coalesced), emit
// W01f (NT=2) and C2f (NT=3, w-cols only) frags with coalesced 16B stores.
// Per-block column counts -> blockCnt[block][24] (non-atomic, deterministic).
// Frag layout: frag[(ktile*NT+nt)*64 + lane][j] = Wc[ktile*32+(lane>>4)*8+j][nt*16+(lane&15)]
__global__ __launch_bounds__(256) void k_fillcnt(const float* __restrict__ w,
                                                 unsigned short* __restrict__ W01f,
                                                 unsigned short* __restrict__ C2f,
                                                 int* __restrict__ blockCnt) {
    __shared__ float wt[4][32 * 24];
    __shared__ int cnt[4][24];
    int wave = threadIdx.x >> 6, lane = threadIdx.x & 63;
    int kt = blockIdx.x * 4 + wave;          // 0..447 (446,447 idle)
    int mycnt = 0;
    if (kt < KT) {
        {   // stage: lane covers 12 floats of the 768-float tile (same-wave LDS, in-order)
            int rloc = lane >> 1;
            int grow = kt * 32 + rloc;
            int grc  = (grow < G) ? grow : (G - 1);
            int col0 = (lane & 1) * 12;
            const float4* src = reinterpret_cast<const float4*>(w + (long)grc * 24 + col0);
            float* dst = &wt[wave][rloc * 24 + col0];
#pragma unroll
            for (int q = 0; q < 3; ++q) {
                float4 v = src[q];
                dst[q * 4 + 0] = v.x; dst[q * 4 + 1] = v.y;
                dst[q * 4 + 2] = v.z; dst[q * 4 + 3] = v.w;
            }
        }
        int r16 = lane & 15, kloc = (lane >> 4) * 8;
#pragma unroll
        for (int nt = 0; nt < 2; ++nt) {
            int col = nt * 16 + r16;
            u16x8 v;
#pragma unroll
            for (int j = 0; j < 8; ++j) {
                int k = kt * 32 + kloc + j;
                bool bit = (k < G) && (col < 24) && (wt[wave][(kloc + j) * 24 + col] > 0.0f);
                v[j] = bit ? (unsigned short)0x3F80 : (unsigned short)0;
            }
            *reinterpret_cast<u16x8*>(W01f + ((long)(kt * 2 + nt) * 64 + lane) * 8) = v;
        }
#pragma unroll
        for (int nt = 0; nt < 2; ++nt) {
            int col = nt * 16 + r16;
            if (col < 24) {
                u16x8 v;
#pragma unroll
                for (int j = 0; j < 8; ++j) {
                    int k = kt * 32 + kloc + j;
                    bool bit = (k < G) && (wt[wave][(kloc + j) * 24 + col] > 0.0f);
                    v[j] = bit ? (unsigned short)0x3F80 : (unsigned short)0;
                }
                *reinterpret_cast<u16x8*>(C2f + ((long)(kt * 3 + nt) * 64 + lane) * 8) = v;
            }
        }
        if (lane < 24) {
#pragma unroll
            for (int r = 0; r < 32; ++r)
                mycnt += ((kt * 32 + r) < G && wt[wave][r * 24 + lane] > 0.0f) ? 1 : 0;
        }
    }
    if (lane < 24) cnt[wave][lane] = mycnt;
    __syncthreads();
    if (threadIdx.x < 24) {
        int t = threadIdx.x;
        blockCnt[blockIdx.x * 24 + t] = cnt[0][t] + cnt[1][t] + cnt[2][t] + cnt[3][t];
    }
}

// ---------------- GEMM core (R7, proven): reg-staged, bf16 LDS, barrierless --

__device__ inline void stage_load(const float* __restrict__ A, int M, int row0,
                                  int k0, bool tail, int wave, int lane,
                                  f32x4u* v) {
    int c4 = (lane & 15) * 4;
#pragma unroll
    for (int m = 0; m < 4; ++m) {
        int grow = row0 + wave * 16 + m * 4 + (lane >> 4);
        grow = (grow < M) ? grow : (M - 1);
        const float* rp = A + (long)grow * G;
        if (!tail) {
            v[m] = *reinterpret_cast<const f32x4u*>(rp + k0 + c4);
        } else {
            f32x4u t;
#pragma unroll
            for (int i = 0; i < 4; ++i) {
                int k = k0 + c4 + i;
                t[i] = rp[(k < G) ? k : (G - 1)];   // k>=G slots hit zero frags
            }
            v[m] = t;
        }
    }
}

__device__ inline void stage_write(unsigned short* buf, float mr,
                                   int wave, int lane, const f32x4u* v) {
#pragma unroll
    for (int m = 0; m < 4; ++m) {
        int row = wave * 16 + m * 4 + (lane >> 4);
        u16x4 b;
#pragma unroll
        for (int i = 0; i < 4; ++i) b[i] = bf16_bits(fminf(v[m][i], mr));
        *reinterpret_cast<u16x4*>(buf + row * LDR + (lane & 15) * 4) = b;
    }
}

template <int NT>
__device__ inline void consume_tiles(const unsigned short* __restrict__ buf,
                                     const unsigned short* __restrict__ Wf,
                                     int ktile0, f32x4* acc, int wave, int lane) {
    int r = lane & 15, sub = lane >> 4;
    const unsigned short* rowp = buf + (wave * 16 + r) * LDR;
#pragma unroll
    for (int kt = 0; kt < 2; ++kt) {
        bf16x8 af = *reinterpret_cast<const bf16x8*>(rowp + kt * 32 + sub * 8);
        const unsigned short* fb = Wf + ((long)((ktile0 + kt) * NT) * 64 + lane) * 8;
#pragma unroll
        for (int nt = 0; nt < NT; ++nt) {
            bf16x8 bfr = *reinterpret_cast<const bf16x8*>(fb + (long)nt * 512);
            acc[nt] = __builtin_amdgcn_mfma_f32_16x16x32_bf16(af, bfr, acc[nt], 0, 0, 0);
        }
    }
}

template <int NT>
__device__ inline void gemm_core(const float* __restrict__ A, int M, int row0,
                                 const unsigned short* __restrict__ Wf, float mr,
                                 int it0, int it1, f32x4* acc,
                                 int wave, int lane) {
    __shared__ __align__(16) unsigned short sb[2][64 * LDR];
#pragma unroll
    for (int nt = 0; nt < NT; ++nt) acc[nt] = (f32x4){0.f, 0.f, 0.f, 0.f};
    f32x4u v[4];
    stage_load(A, M, row0, it0 * 64, it0 == NIT - 1, wave, lane, v);
    stage_write(sb[0], mr, wave, lane, v);
    int cur = 0;
    for (int it = it0; it < it1 - 1; ++it) {
        int nxt = it + 1;
        stage_load(A, M, row0, nxt * 64, nxt == NIT - 1, wave, lane, v);
        consume_tiles<NT>(sb[cur], Wf, it * 2, acc, wave, lane);
        stage_write(sb[cur ^ 1], mr, wave, lane, v);
        cur ^= 1;
    }
    consume_tiles<NT>(sb[cur], Wf, (it1 - 1) * 2, acc, wave, lane);
}

// merged: B-GEMM (split 8 -> p1 partials) + rank GEMM (split 16 -> rp partials)
// rank blocks compute maxrank in a prologue from blockCnt (exact int arithmetic).
__global__ __launch_bounds__(256) void k_gemm2(
    const float* __restrict__ Bmat, const float* __restrict__ xrank,
    const unsigned short* __restrict__ W01f, const int* __restrict__ blockCnt,
    const float* __restrict__ maxrank_p,
    float* __restrict__ p1, float* __restrict__ rp) {
    int bid = blockIdx.x;
    int wave = threadIdx.x >> 6, lane = threadIdx.x & 63;
    int r16 = lane & 15, sub = lane >> 4;
    f32x4 acc[2];
    const float* A;
    int M, mblk, it0, it1;
    float mr;
    float* outp;
    if (bid < MB1 * S1) {
        mblk = bid >> 3; int split = bid & 7;
        it0 = split * IPS1; it1 = min(it0 + IPS1, NIT);
        A = Bmat; M = G; mr = FMAX;
        outp = p1 + (long)split * GP * 32;
    } else {
        // prologue: n[h] from blockCnt -> nmax -> maxrank
        __shared__ int ncnt[24];
        __shared__ float smr;
        if (threadIdx.x < 24) {
            int n = 0;
            for (int b = 0; b < NFC; ++b) n += blockCnt[b * 24 + threadIdx.x];
            ncnt[threadIdx.x] = n;
        }
        __syncthreads();
        if (threadIdx.x == 0) {
            int nm = 0;
#pragma unroll
            for (int h = 0; h < H; ++h) nm = max(nm, ncnt[h]);
            float mp = maxrank_p[0];
            if (mp < 0.0f) mp = 0.0f;
            smr = (float)nm + 10.0f + mp * 1000.0f;
        }
        __syncthreads();
        int t = bid - MB1 * S1;
        mblk = t >> 4; int split = t & 15;
        it0 = split * IPSX; it1 = min(it0 + IPSX, NIT);
        A = xrank; M = BATCH; mr = smr;
        outp = rp + (long)split * BATCH * 32;
    }
    int row0 = mblk * 64;
    gemm_core<2>(A, M, row0, W01f, mr, it0, it1, acc, wave, lane);
    int orow0 = row0 + wave * 16 + sub * 4;
#pragma unroll
    for (int nt = 0; nt < 2; ++nt)
#pragma unroll
        for (int rr = 0; rr < 4; ++rr) {
            int orow = orow0 + rr;
            if (orow < M) outp[(long)orow * 32 + nt * 16 + r16] = acc[nt][rr];
        }
}

__global__ __launch_bounds__(256) void k_gemm3(
    const float* __restrict__ xlog2, const unsigned short* __restrict__ C2f,
    float* __restrict__ lp) {
    int bid = blockIdx.x;
    int wave = threadIdx.x >> 6, lane = threadIdx.x & 63;
    int r16 = lane & 15, sub = lane >> 4;
    int mblk = bid >> 4, split = bid & 15;
    int it0 = split * IPSX;
    int it1 = min(it0 + IPSX, NIT);
    int row0 = mblk * 64;
    f32x4 acc[3];
    gemm_core<3>(xlog2, BATCH, row0, C2f, FMAX, it0, it1, acc, wave, lane);
    float* outp = lp + (long)split * BATCH * 48;
    int orow0 = row0 + wave * 16 + sub * 4;
#pragma unroll
    for (int nt = 0; nt < 3; ++nt)
#pragma unroll
        for (int rr = 0; rr < 4; ++rr)
            outp[(long)(orow0 + rr) * 48 + nt * 16 + r16] = acc[nt][rr];
}

// reduce B-GEMM k-split partials -> gs (bf16 into C2f frag cols 24..47) + block S partials
__global__ __launch_bounds__(256) void k_reduce1(const float* __restrict__ p1,
                                                 unsigned short* __restrict__ C2f,
                                                 float* __restrict__ blockS) {
    int k = blockIdx.x * 256 + threadIdx.x;  // enumerates frag k-slots
    float gsr[H];
#pragma unroll
    for (int h = 0; h < H; ++h) gsr[h] = 0.0f;
    if (k < GP) {
        if (k < G) {
            for (int sp = 0; sp < S1; ++sp) {
                const float4* r4 = reinterpret_cast<const float4*>(
                    p1 + ((long)sp * GP + k) * 32);
#pragma unroll
                for (int q = 0; q < 6; ++q) {
                    float4 v = r4[q];
                    gsr[q * 4 + 0] += v.x;
                    gsr[q * 4 + 1] += v.y;
                    gsr[q * 4 + 2] += v.z;
                    gsr[q * 4 + 3] += v.w;
                }
            }
        }
        int ktile = k >> 5, j = k & 7, lsub = (k >> 3) & 3;
#pragma unroll
        for (int h = 0; h < H; ++h) {
            unsigned short bits = bf16_bits(gsr[h]);
            int col = 24 + h, nt = col >> 4, lane = lsub * 16 + (col & 15);
            C2f[((long)(ktile * 3 + nt) * 64 + lane) * 8 + j] = bits;
            gsr[h] = bits_to_f32(bits);  // S from the rounded values (self-consistent)
        }
    }
    // deterministic reduction: wave shfl tree, then cross-wave via LDS
    __shared__ float sred[4][H];
    int lane = threadIdx.x & 63, w = threadIdx.x >> 6;
#pragma unroll
    for (int h = 0; h < H; ++h) {
        float v = gsr[h];
        for (int off = 1; off < 64; off <<= 1) v += __shfl_xor(v, off);
        if (lane == 0) sred[w][h] = v;
    }
    __syncthreads();
    if (threadIdx.x < H) {
        float s = sred[0][threadIdx.x] + sred[1][threadIdx.x] +
                  sred[2][threadIdx.x] + sred[3][threadIdx.x];
        blockS[blockIdx.x * H + threadIdx.x] = s;
    }
}

// reduce x-GEMM partials, apply UCell/AMS transforms -> R_all [4096 x 48]
// constants computed in-block from blockCnt/blockS (bit-identical to old k_consts/k_sumS)
__global__ __launch_bounds__(256) void k3a(const float* __restrict__ rp,
                                           const float* __restrict__ lp,
                                           const int* __restrict__ blockCnt,
                                           const float* __restrict__ blockS,
                                           const float* __restrict__ maxrank_p,
                                           float* __restrict__ R_all) {
    __shared__ int ncnt[24];
    __shared__ float cA[24], cC[24], cI[24], cS[24];
    int t = threadIdx.x;
    if (t < 24) {
        int n = 0;
        for (int b = 0; b < NFC; ++b) n += blockCnt[b * 24 + t];
        ncnt[t] = n;
        float s = 0.0f;
        for (int b = 0; b < NRD; ++b) s += blockS[b * 24 + t];
        cS[t] = s;
    }
    __syncthreads();
    if (t < 24) {
        int nm = 0;
#pragma unroll
        for (int h = 0; h < H; ++h) nm = max(nm, ncnt[h]);
        float mp = maxrank_p[0];
        if (mp < 0.0f) mp = 0.0f;
        float mrk = (float)nm + 10.0f + mp * 1000.0f;
        float nf = (float)ncnt[t];
        float c1 = nf * (nf + 1.0f) * 0.5f;
        float c2 = 1.0f / (nf * mrk);
        cA[t] = 1.0f + c1 * c2;
        cC[t] = c2;
        cI[t] = 1.0f / nf;
    }
    __syncthreads();
    int e = blockIdx.x * 256 + threadIdx.x;
    if (e >= BATCH * 48) return;
    int b = e / 48, c = e % 48;
    float v;
    if (c < 24) {
        float s = 0.0f;
        for (int sp = 0; sp < SX; ++sp) s += rp[((long)sp * BATCH + b) * 32 + c];
        v = cA[c] - s * cC[c];
    } else {
        int h = c - 24;
        float raw = 0.0f, bg = 0.0f;
        for (int sp = 0; sp < SX; ++sp) {
            const float* base = lp + ((long)sp * BATCH + b) * 48;
            raw += base[h];
            bg  += base[24 + h];
        }
        v = raw * cI[h] - bg / cS[h];
    }
    R_all[e] = v;
}

// per-column batch stats (f64), fold out_w into coef -> cstats[mu:0..47, coef:48..95]
__global__ __launch_bounds__(256) void k3b(const float* __restrict__ R_all,
                                           const float* __restrict__ out_w,
                                           float* __restrict__ cstats) {
    int c = blockIdx.x;
    double s = 0.0, s2 = 0.0;
    for (int b = threadIdx.x; b < BATCH; b += 256) {
        double x = (double)R_all[(long)b * 48 + c];
        s += x; s2 += x * x;
    }
    __shared__ double sh1[256], sh2[256];
    sh1[threadIdx.x] = s; sh2[threadIdx.x] = s2;
    __syncthreads();
    for (int off = 128; off > 0; off >>= 1) {
        if (threadIdx.x < off) {
            sh1[threadIdx.x] += sh1[threadIdx.x + off];
            sh2[threadIdx.x] += sh2[threadIdx.x + off];
        }
        __syncthreads();
    }
    if (threadIdx.x == 0) {
        double mu  = sh1[0] / (double)BATCH;
        double var = sh2[0] / (double)BATCH - mu * mu;
        float rs = (float)(1.0 / sqrt(var + 1e-5));
        cstats[c]      = (float)mu;
        cstats[48 + c] = out_w[c] * rs;
    }
}

__global__ void k3c(const float* __restrict__ R_all, const float* __restrict__ cstats,
                    const float* __restrict__ out_b, float* __restrict__ out) {
    int b = blockIdx.x * blockDim.x + threadIdx.x;
    if (b < BATCH) {
        float acc = out_b[0];
#pragma unroll
        for (int c = 0; c < 48; ++c)
            acc += cstats[48 + c] * (R_all[(long)b * 48 + c] - cstats[c]);
        out[b] = acc;
    }
}

// ---------------- launch (7 dispatches) ----------------

extern "C" void kernel_launch(void* const* d_in, const int* in_sizes, int n_in,
                              void* d_out, int out_size, void* d_ws, size_t ws_size,
                              hipStream_t stream) {
    const float* x_rank    = (const float*)d_in[0];
    const float* x_log2    = (const float*)d_in[1];
    const float* Bmat      = (const float*)d_in[2];
    const float* weight    = (const float*)d_in[3];
    const float* maxrank_p = (const float*)d_in[4];
    const float* out_w     = (const float*)d_in[5];
    const float* out_b     = (const float*)d_in[6];

    char* ws = (char*)d_ws;
    size_t off = 0;
    auto alloc = [&](size_t bytes) {
        void* p = (void*)(ws + off);
        off = (off + bytes + 255) & ~(size_t)255;
        return p;
    };
    int*            blockCnt = (int*)alloc((size_t)NFC * 24 * 4);
    float*          blockS   = (float*)alloc((size_t)NRD * 24 * 4);
    float*          cstats   = (float*)alloc(96 * 4);
    unsigned short* W01f     = (unsigned short*)alloc((size_t)KT * 2 * 64 * 8 * 2);
    unsigned short* C2f      = (unsigned short*)alloc((size_t)KT * 3 * 64 * 8 * 2);
    float*          p1       = (float*)alloc((size_t)S1 * GP * 32 * 4);
    float*          rp       = (float*)alloc((size_t)SX * BATCH * 32 * 4);
    float*          lp       = (float*)alloc((size_t)SX * BATCH * 48 * 4);
    float*          R_all    = (float*)alloc((size_t)BATCH * 48 * 4);
    (void)ws_size; (void)in_sizes; (void)n_in; (void)out_size;

    k_fillcnt <<<NFC, 256, 0, stream>>>(weight, W01f, C2f, blockCnt);
    k_gemm2   <<<MB1 * S1 + MBX * SX, 256, 0, stream>>>(Bmat, x_rank, W01f, blockCnt,
                                                        maxrank_p, p1, rp);
    k_reduce1 <<<NRD, 256, 0, stream>>>(p1, C2f, blockS);
    k_gemm3   <<<MBX * SX, 256, 0, stream>>>(x_log2, C2f, lp);
    k3a       <<<BATCH * 48 / 256, 256, 0, stream>>>(rp, lp, blockCnt, blockS,
                                                     maxrank_p, R_all);
    k3b       <<<48, 256, 0, stream>>>(R_all, out_w, cstats);
    k3c       <<<16, 256, 0, stream>>>(R_all, cstats, out_b, (float*)d_out);
}